// Round 6
// baseline (408.569 us; speedup 1.0000x reference)
//
#include <hip/hip_runtime.h>

// out[128,16384] = [A|B](128x8384) @ [x; x2](8384x16384), bf16 MFMA.
// Round 6 = round 5 (barrier-free K-loop, permuted K, register B-frag gen) +
//   - split-K x8  -> 2048 blocks = 8 blocks/CU = 32 waves/CU (launch_bounds(256,8))
//   - packed gen: v_pk_mul_f32 (float2) + v_perm_b32 truncation pack (1 op / 2 elems)
//   - staging uses ds_write_b128 (4 writes instead of 32)
//   - memset + perm-table build fused into one kernel (3 dispatches total)
// K permutation: identity k'<128 (steps 0-1) | NICE [128,7936) (steps 2-123,
// uniform i, aligned j-octet) | RAGGED [7936,8384) (steps 124-130, gather).

constexpr int N_     = 128;
constexpr int S_     = 8256;
constexpr int BATCH_ = 16384;
constexpr int KTOT   = 8384;         // 131*64
constexpr int NKT    = 131;
constexpr int NSPLIT = 8;            // splits 0-2: 17 steps, 3-7: 16 steps
constexpr int LD     = 136;          // xt row stride (ushorts); 272B rows -> dense b128
constexpr size_t WT_BYTES = (size_t)KTOT * 128 * 2;
constexpr size_t PP_OFF   = WT_BYTES;

typedef __attribute__((ext_vector_type(8))) short short8;
typedef __attribute__((ext_vector_type(4))) float f32x4;
typedef __attribute__((ext_vector_type(2))) float f32x2;

__device__ __forceinline__ float bf2f(ushort h) {
    unsigned u = (unsigned)h << 16;
    float f;
    __builtin_memcpy(&f, &u, 4);
    return f;
}
__device__ __forceinline__ ushort f2bf(float f) {   // RNE (used in staging/build only)
    unsigned u;
    __builtin_memcpy(&u, &f, 4);
    u = (u + 0x7FFFu + ((u >> 16) & 1u)) >> 16;
    return (ushort)u;
}
__device__ __forceinline__ uint fbits(float f) {
    uint u; __builtin_memcpy(&u, &f, 4); return u;
}

// ---------- phase 0: zero out + build perm table (fused) ----------
// pp[k'] = i | (j<<8);  j==0xFF marks identity (value = x[i]).
__global__ void zero_and_perm(float* __restrict__ out, ushort* __restrict__ pp) {
    const int b = blockIdx.x;
    if (b < 2048) {
        ((float4*)out)[b * 256 + threadIdx.x] = make_float4(0.f, 0.f, 0.f, 0.f);
        return;
    }
    const int i = threadIdx.x;
    if (i >= 128) return;
    pp[i] = (ushort)(i | (0xFFu << 8));
    int off_n = 0, off_r = 0;
    for (int q = 0; q < i; ++q) {
        off_n += 16 - ((q + 7) >> 3);
        off_r += (8 - (q & 7)) & 7;
    }
    const int jb0 = (i + 7) >> 3;
    const int kb = 128 + off_n * 8;
    for (int jb = jb0; jb < 16; ++jb) {
        const int j0 = jb * 8;
        for (int e = 0; e < 8; ++e)
            pp[kb + (jb - jb0) * 8 + e] = (ushort)(i | ((j0 + e) << 8));
    }
    const int h = (8 - (i & 7)) & 7;
    const int rb = 7936 + off_r;
    for (int e = 0; e < h; ++e)
        pp[rb + e] = (ushort)(i | ((i + e) << 8));
}

// ---------- phase 1: W -> bf16, K-tiled in PERMUTED order ----------
__global__ void build_wt(const float* __restrict__ A, const float* __restrict__ B,
                         const ushort* __restrict__ pp, ushort* __restrict__ wt) {
    int e  = blockIdx.x * 256 + threadIdx.x;   // 131*8192 = 4192*256 exactly
    int kt = e >> 13;
    int p  = e & 8191;
    int m  = p >> 6;
    int kl = p & 63;
    uint pr = pp[kt * 64 + kl];
    uint i = pr & 0xFFu, j = pr >> 8;
    float v;
    if (j == 0xFFu) v = A[m * 128 + i];
    else {
        int s = (int)(i * (257 - i) / 2 + (j - i));
        v = B[(size_t)m * S_ + s];
    }
    wt[e] = f2bf(v);
}

// ---------- phase 2: fused MFMA GEMM, barrier-free K-loop, split-K x8 ----------
__global__ __launch_bounds__(256, 8) void gemm_mfma(
    const float*  __restrict__ x,
    const ushort* __restrict__ wt,
    const ushort* __restrict__ pp,
    float* __restrict__ out)
{
    __shared__ ushort xt[64 * LD];     // xt[n*LD + r] = bf16 x[r][b0+n], 17 KB

    const int t    = threadIdx.x;
    const int b0   = blockIdx.x * 64;
    const int sp   = blockIdx.y;
    const int kt0  = sp * 16 + (sp < 3 ? sp : 3);
    const int kt1  = kt0 + 16 + (sp < 3 ? 1 : 0);
    const int lane = t & 63;
    const int w    = t >> 6;
    const int wm   = w >> 1, wn = w & 1;
    const int l16  = lane & 15, quad = lane >> 4;
    const int n    = t & 63;

    // ---- stage xt: coalesced dword loads, RNE, packed b128 LDS writes ----
    #pragma unroll
    for (int c = 0; c < 4; ++c) {
        const int rb = w * 32 + c * 8;
        uint ow[4];
        #pragma unroll
        for (int p = 0; p < 4; ++p) {
            const ushort u0 = f2bf(x[(size_t)(rb + 2 * p) * BATCH_ + b0 + n]);
            const ushort u1 = f2bf(x[(size_t)(rb + 2 * p + 1) * BATCH_ + b0 + n]);
            ow[p] = (uint)u0 | ((uint)u1 << 16);
        }
        __builtin_memcpy(&xt[n * LD + rb], ow, 16);   // 16B-aligned (LD*2=272=16*17)
    }
    __syncthreads();

    f32x4 acc[4][2];
    #pragma unroll
    for (int mt = 0; mt < 4; ++mt)
        #pragma unroll
        for (int nt = 0; nt < 2; ++nt)
            acc[mt][nt] = (f32x4){0.f, 0.f, 0.f, 0.f};

    const ushort* xr0 = xt + (wn * 32 + l16) * LD;
    const ushort* xr1 = xr0 + 16 * LD;

    for (int kt = kt0; kt < kt1; ++kt) {
        // ---- A-frags from L2-resident wt ----
        short8 af[8];
        {
            const ushort* ab = wt + (size_t)kt * 8192 + quad * 8;
            #pragma unroll
            for (int kk = 0; kk < 2; ++kk)
                #pragma unroll
                for (int mt = 0; mt < 4; ++mt)
                    af[kk * 4 + mt] =
                        *(const short8*)(ab + (wm * 64 + mt * 16 + l16) * 64 + kk * 32);
        }

        // ---- generate B-frags in registers (packed math + perm pack) ----
        short8 bfr[2][2];
        #pragma unroll
        for (int kk = 0; kk < 2; ++kk) {
            const int k0 = kt * 64 + kk * 32 + quad * 8;
            const uint4 pk = *(const uint4*)(pp + k0);    // 8 pairs, 16B, quad-uniform
            const uint p0 = pk.x & 0xFFFFu, p7 = pk.w >> 16;
            const uint i0 = p0 & 0xFFu, j0 = p0 >> 8;
            #pragma unroll
            for (int nt = 0; nt < 2; ++nt) {
                const ushort* xr = nt ? xr1 : xr0;
                if (j0 == 0xFFu) {
                    bfr[kk][nt] = *(const short8*)(xr + i0);          // identity octet
                } else if ((p7 & 0xFFu) == i0) {                      // NICE octet
                    const float xi = bf2f(xr[i0]);
                    const f32x2 xi2 = {xi, xi};
                    uint wsx[4];
                    __builtin_memcpy(wsx, xr + j0, 16);               // ds_read_b128
                    uint ow[4];
                    #pragma unroll
                    for (int p = 0; p < 4; ++p) {
                        const uint lo = wsx[p] << 16;
                        const uint hi = wsx[p] & 0xFFFF0000u;
                        f32x2 a;
                        { float fl, fh;
                          __builtin_memcpy(&fl, &lo, 4);
                          __builtin_memcpy(&fh, &hi, 4);
                          a.x = fl; a.y = fh; }
                        const f32x2 o = a * xi2;                      // v_pk_mul_f32
                        ow[p] = __builtin_amdgcn_perm(fbits(o.y), fbits(o.x),
                                                      0x07060302u);   // hi16|hi16
                    }
                    __builtin_memcpy(&bfr[kk][nt], ow, 16);
                } else {                                              // RAGGED octet
                    const uint pr4[4] = {pk.x, pk.y, pk.z, pk.w};
                    float prods[8];
                    #pragma unroll
                    for (int e = 0; e < 8; ++e) {
                        const uint ent = (pr4[e >> 1] >> ((e & 1) * 16)) & 0xFFFFu;
                        prods[e] = bf2f(xr[ent & 0xFFu]) * bf2f(xr[ent >> 8]);
                    }
                    uint ow[4];
                    #pragma unroll
                    for (int p = 0; p < 4; ++p)
                        ow[p] = __builtin_amdgcn_perm(fbits(prods[2 * p + 1]),
                                                      fbits(prods[2 * p]),
                                                      0x07060302u);
                    __builtin_memcpy(&bfr[kk][nt], ow, 16);
                }
            }
        }

        // ---- MFMA ----
        #pragma unroll
        for (int kk = 0; kk < 2; ++kk)
            #pragma unroll
            for (int mt = 0; mt < 4; ++mt)
                #pragma unroll
                for (int nt = 0; nt < 2; ++nt)
                    acc[mt][nt] = __builtin_amdgcn_mfma_f32_16x16x32_bf16(
                        af[kk * 4 + mt], bfr[kk][nt], acc[mt][nt], 0, 0, 0);
    }

    // ---- epilogue: atomic accumulate (C/D: col=lane&15, row=quad*4+reg) ----
    #pragma unroll
    for (int mt = 0; mt < 4; ++mt) {
        #pragma unroll
        for (int nt = 0; nt < 2; ++nt) {
            const int mbase = wm * 64 + mt * 16 + quad * 4;
            const size_t col = (size_t)b0 + wn * 32 + nt * 16 + l16;
            #pragma unroll
            for (int r = 0; r < 4; ++r)
                unsafeAtomicAdd(&out[(size_t)(mbase + r) * BATCH_ + col],
                                acc[mt][nt][r]);
        }
    }
}

extern "C" void kernel_launch(void* const* d_in, const int* in_sizes, int n_in,
                              void* d_out, int out_size, void* d_ws, size_t ws_size,
                              hipStream_t stream) {
    const float* x = (const float*)d_in[0];   // [128, 16384]
    const float* A = (const float*)d_in[1];   // [128, 128]
    const float* B = (const float*)d_in[2];   // [128, 8256]
    float* out = (float*)d_out;               // [128, 16384]

    ushort* wt = (ushort*)d_ws;
    ushort* pp = (ushort*)((char*)d_ws + PP_OFF);

    zero_and_perm<<<2049, 256, 0, stream>>>(out, pp);
    build_wt<<<4192, 256, 0, stream>>>(A, B, pp, wt);
    gemm_mfma<<<dim3(BATCH_ / 64, NSPLIT), 256, 0, stream>>>(x, wt, pp, out);
}

// Round 7
// 230.766 us; speedup vs baseline: 1.7705x; 1.7705x over previous
//
#include <hip/hip_runtime.h>

// out[128,16384] = [A|B](128x8384) @ [x; x2](8384x16384), bf16 MFMA.
// Round 7 = round 5 (barrier-free K-loop, permuted K, register B-frag gen,
//                    hipMemsetAsync + build_perm + build_wt, NO min-wave hint)
//         + round 6's packed gen (v_pk_mul_f32 + v_perm_b32 truncation pack)
//         + split-K x8 via grid (2048 blocks = 8 blocks/CU; VGPR ~56 allows 8 w/SIMD)
// DO NOT add __launch_bounds__ min-waves: (256,8) clamped VGPR to 32 -> 1.5 GB spills (r6).
// K permutation: identity k'<128 | NICE [128,7936) uniform-i aligned-j octets |
// RAGGED [7936,8384) gather (7 of 131 steps).

constexpr int N_     = 128;
constexpr int S_     = 8256;
constexpr int BATCH_ = 16384;
constexpr int KTOT   = 8384;         // 131*64
constexpr int NKT    = 131;
constexpr int NSPLIT = 8;            // splits 0-2: 17 steps, 3-7: 16 steps
constexpr int LD     = 136;          // xt row stride (ushorts); rows 272B = 17x16B
constexpr size_t WT_BYTES = (size_t)KTOT * 128 * 2;
constexpr size_t PP_OFF   = WT_BYTES;

typedef __attribute__((ext_vector_type(8))) short short8;
typedef __attribute__((ext_vector_type(4))) float f32x4;
typedef __attribute__((ext_vector_type(2))) float f32x2;

__device__ __forceinline__ float bf2f(ushort h) {
    unsigned u = (unsigned)h << 16;
    float f;
    __builtin_memcpy(&f, &u, 4);
    return f;
}
__device__ __forceinline__ ushort f2bf(float f) {   // RNE (staging/build only)
    unsigned u;
    __builtin_memcpy(&u, &f, 4);
    u = (u + 0x7FFFu + ((u >> 16) & 1u)) >> 16;
    return (ushort)u;
}
__device__ __forceinline__ uint fbits(float f) {
    uint u; __builtin_memcpy(&u, &f, 4); return u;
}

// ---------- phase 1a: permuted pair table pp[k'] = i | (j<<8) ----------
__global__ void build_perm(ushort* __restrict__ pp) {
    int i = threadIdx.x;
    if (i >= 128) return;
    pp[i] = (ushort)(i | (0xFFu << 8));
    int off_n = 0, off_r = 0;
    for (int q = 0; q < i; ++q) {
        off_n += 16 - ((q + 7) >> 3);
        off_r += (8 - (q & 7)) & 7;
    }
    const int jb0 = (i + 7) >> 3;
    const int kb = 128 + off_n * 8;
    for (int jb = jb0; jb < 16; ++jb) {
        const int j0 = jb * 8;
        for (int e = 0; e < 8; ++e)
            pp[kb + (jb - jb0) * 8 + e] = (ushort)(i | ((j0 + e) << 8));
    }
    const int h = (8 - (i & 7)) & 7;
    const int rb = 7936 + off_r;
    for (int e = 0; e < h; ++e)
        pp[rb + e] = (ushort)(i | ((i + e) << 8));
}

// ---------- phase 1b: W -> bf16, K-tiled in PERMUTED order ----------
__global__ void build_wt(const float* __restrict__ A, const float* __restrict__ B,
                         const ushort* __restrict__ pp, ushort* __restrict__ wt) {
    int e  = blockIdx.x * 256 + threadIdx.x;   // 131*8192 = 4192*256 exactly
    int kt = e >> 13;
    int p  = e & 8191;
    int m  = p >> 6;
    int kl = p & 63;
    uint pr = pp[kt * 64 + kl];
    uint i = pr & 0xFFu, j = pr >> 8;
    float v;
    if (j == 0xFFu) v = A[m * 128 + i];
    else {
        int s = (int)(i * (257 - i) / 2 + (j - i));
        v = B[(size_t)m * S_ + s];
    }
    wt[e] = f2bf(v);
}

// ---------- phase 2: fused MFMA GEMM, barrier-free K-loop, split-K x8 ----------
__global__ __launch_bounds__(256) void gemm_mfma(
    const float*  __restrict__ x,
    const ushort* __restrict__ wt,
    const ushort* __restrict__ pp,
    float* __restrict__ out)
{
    __shared__ ushort xt[64 * LD];     // xt[n*LD + r] = bf16 x[r][b0+n], 17 KB

    const int t    = threadIdx.x;
    const int b0   = blockIdx.x * 64;
    const int sp   = blockIdx.y;
    const int kt0  = sp * 16 + (sp < 3 ? sp : 3);
    const int kt1  = kt0 + 16 + (sp < 3 ? 1 : 0);
    const int lane = t & 63;
    const int w    = t >> 6;
    const int wm   = w >> 1, wn = w & 1;
    const int l16  = lane & 15, quad = lane >> 4;
    const int n    = t & 63;

    // ---- stage xt: coalesced dword loads, RNE, packed b128 LDS writes ----
    #pragma unroll
    for (int c = 0; c < 4; ++c) {
        const int rb = w * 32 + c * 8;
        uint ow[4];
        #pragma unroll
        for (int p = 0; p < 4; ++p) {
            const ushort u0 = f2bf(x[(size_t)(rb + 2 * p) * BATCH_ + b0 + n]);
            const ushort u1 = f2bf(x[(size_t)(rb + 2 * p + 1) * BATCH_ + b0 + n]);
            ow[p] = (uint)u0 | ((uint)u1 << 16);
        }
        __builtin_memcpy(&xt[n * LD + rb], ow, 16);
    }
    __syncthreads();

    f32x4 acc[4][2];
    #pragma unroll
    for (int mt = 0; mt < 4; ++mt)
        #pragma unroll
        for (int nt = 0; nt < 2; ++nt)
            acc[mt][nt] = (f32x4){0.f, 0.f, 0.f, 0.f};

    const ushort* xr0 = xt + (wn * 32 + l16) * LD;
    const ushort* xr1 = xr0 + 16 * LD;

    for (int kt = kt0; kt < kt1; ++kt) {
        // ---- A-frags from L2-resident wt ----
        short8 af[8];
        {
            const ushort* ab = wt + (size_t)kt * 8192 + quad * 8;
            #pragma unroll
            for (int kk = 0; kk < 2; ++kk)
                #pragma unroll
                for (int mt = 0; mt < 4; ++mt)
                    af[kk * 4 + mt] =
                        *(const short8*)(ab + (wm * 64 + mt * 16 + l16) * 64 + kk * 32);
        }

        // ---- generate B-frags in registers (packed math + perm pack) ----
        short8 bfr[2][2];
        #pragma unroll
        for (int kk = 0; kk < 2; ++kk) {
            const int k0 = kt * 64 + kk * 32 + quad * 8;
            const uint4 pk = *(const uint4*)(pp + k0);    // 8 pairs, quad-uniform
            const uint p0 = pk.x & 0xFFFFu, p7 = pk.w >> 16;
            const uint i0 = p0 & 0xFFu, j0 = p0 >> 8;
            #pragma unroll
            for (int nt = 0; nt < 2; ++nt) {
                const ushort* xr = nt ? xr1 : xr0;
                if (j0 == 0xFFu) {
                    bfr[kk][nt] = *(const short8*)(xr + i0);          // identity octet
                } else if ((p7 & 0xFFu) == i0) {                      // NICE octet
                    const float xi = bf2f(xr[i0]);
                    const f32x2 xi2 = {xi, xi};
                    uint wsx[4];
                    __builtin_memcpy(wsx, xr + j0, 16);               // ds_read_b128
                    uint ow[4];
                    #pragma unroll
                    for (int p = 0; p < 4; ++p) {
                        const uint lo = wsx[p] << 16;
                        const uint hi = wsx[p] & 0xFFFF0000u;
                        f32x2 a;
                        { float fl, fh;
                          __builtin_memcpy(&fl, &lo, 4);
                          __builtin_memcpy(&fh, &hi, 4);
                          a.x = fl; a.y = fh; }
                        const f32x2 o = a * xi2;                      // v_pk_mul_f32
                        ow[p] = __builtin_amdgcn_perm(fbits(o.y), fbits(o.x),
                                                      0x07060302u);   // hi16|hi16
                    }
                    __builtin_memcpy(&bfr[kk][nt], ow, 16);
                } else {                                              // RAGGED octet
                    const uint pr4[4] = {pk.x, pk.y, pk.z, pk.w};
                    float prods[8];
                    #pragma unroll
                    for (int e = 0; e < 8; ++e) {
                        const uint ent = (pr4[e >> 1] >> ((e & 1) * 16)) & 0xFFFFu;
                        prods[e] = bf2f(xr[ent & 0xFFu]) * bf2f(xr[ent >> 8]);
                    }
                    uint ow[4];
                    #pragma unroll
                    for (int p = 0; p < 4; ++p)
                        ow[p] = __builtin_amdgcn_perm(fbits(prods[2 * p + 1]),
                                                      fbits(prods[2 * p]),
                                                      0x07060302u);
                    __builtin_memcpy(&bfr[kk][nt], ow, 16);
                }
            }
        }

        // ---- MFMA ----
        #pragma unroll
        for (int kk = 0; kk < 2; ++kk)
            #pragma unroll
            for (int mt = 0; mt < 4; ++mt)
                #pragma unroll
                for (int nt = 0; nt < 2; ++nt)
                    acc[mt][nt] = __builtin_amdgcn_mfma_f32_16x16x32_bf16(
                        af[kk * 4 + mt], bfr[kk][nt], acc[mt][nt], 0, 0, 0);
    }

    // ---- epilogue: atomic accumulate (C/D: col=lane&15, row=quad*4+reg) ----
    #pragma unroll
    for (int mt = 0; mt < 4; ++mt) {
        #pragma unroll
        for (int nt = 0; nt < 2; ++nt) {
            const int mbase = wm * 64 + mt * 16 + quad * 4;
            const size_t col = (size_t)b0 + wn * 32 + nt * 16 + l16;
            #pragma unroll
            for (int r = 0; r < 4; ++r)
                unsafeAtomicAdd(&out[(size_t)(mbase + r) * BATCH_ + col],
                                acc[mt][nt][r]);
        }
    }
}

extern "C" void kernel_launch(void* const* d_in, const int* in_sizes, int n_in,
                              void* d_out, int out_size, void* d_ws, size_t ws_size,
                              hipStream_t stream) {
    const float* x = (const float*)d_in[0];   // [128, 16384]
    const float* A = (const float*)d_in[1];   // [128, 128]
    const float* B = (const float*)d_in[2];   // [128, 8256]
    float* out = (float*)d_out;               // [128, 16384]

    ushort* wt = (ushort*)d_ws;
    ushort* pp = (ushort*)((char*)d_ws + PP_OFF);

    hipMemsetAsync(out, 0, (size_t)N_ * BATCH_ * sizeof(float), stream);
    build_perm<<<1, 128, 0, stream>>>(pp);
    build_wt<<<4192, 256, 0, stream>>>(A, B, pp, wt);
    gemm_mfma<<<dim3(BATCH_ / 64, NSPLIT), 256, 0, stream>>>(x, wt, pp, out);
}

// Round 8
// 205.424 us; speedup vs baseline: 1.9889x; 1.1234x over previous
//
#include <hip/hip_runtime.h>

// out[128,16384] = [A|B](128x8384) @ [x; x2](8384x16384), bf16 MFMA.
// Round 8 = round 7 minus its regressions, plus a de-serialized K-loop:
//   - split-K x4 (r5 config; r7's x8 only doubled prologue+atomic overhead,
//     occupancy is register-capped at ~5 waves/SIMD: 52 VGPR + 32 AGPR)
//   - K-loop split into 3 BRANCH-FREE phase loops (identity / NICE / ragged):
//     NICE body is straight-line, so all 8 gen LDS reads batch under one
//     lgkmcnt window and overlap the af global loads
//   - pp pair-words register-prefetched one step ahead (breaks L2->LDS chain)
// DO NOT add __launch_bounds__ min-waves: (256,8) clamped VGPR -> spills (r6).
// K permutation: identity k'<128 (steps 0-1) | NICE [128,7936) (steps 2-123,
// uniform i, aligned j-octet) | RAGGED [7936,8384) (steps 124-130, gather).

constexpr int N_     = 128;
constexpr int S_     = 8256;
constexpr int BATCH_ = 16384;
constexpr int KTOT   = 8384;         // 131*64
constexpr int NKT    = 131;
constexpr int NSPLIT = 4;            // splits: 33,33,33,32 steps
constexpr int LD     = 136;          // xt row stride (ushorts); rows 272B = 17x16B
constexpr size_t WT_BYTES = (size_t)KTOT * 128 * 2;
constexpr size_t PP_OFF   = WT_BYTES;

typedef __attribute__((ext_vector_type(8))) short short8;
typedef __attribute__((ext_vector_type(4))) float f32x4;
typedef __attribute__((ext_vector_type(2))) float f32x2;

__device__ __forceinline__ float bf2f(ushort h) {
    unsigned u = (unsigned)h << 16;
    float f;
    __builtin_memcpy(&f, &u, 4);
    return f;
}
__device__ __forceinline__ ushort f2bf(float f) {   // RNE (staging/build only)
    unsigned u;
    __builtin_memcpy(&u, &f, 4);
    u = (u + 0x7FFFu + ((u >> 16) & 1u)) >> 16;
    return (ushort)u;
}
__device__ __forceinline__ uint fbits(float f) {
    uint u; __builtin_memcpy(&u, &f, 4); return u;
}

// ---------- phase 1a: permuted pair table pp[k'] = i | (j<<8) ----------
__global__ void build_perm(ushort* __restrict__ pp) {
    int i = threadIdx.x;
    if (i >= 128) return;
    pp[i] = (ushort)(i | (0xFFu << 8));
    int off_n = 0, off_r = 0;
    for (int q = 0; q < i; ++q) {
        off_n += 16 - ((q + 7) >> 3);
        off_r += (8 - (q & 7)) & 7;
    }
    const int jb0 = (i + 7) >> 3;
    const int kb = 128 + off_n * 8;
    for (int jb = jb0; jb < 16; ++jb) {
        const int j0 = jb * 8;
        for (int e = 0; e < 8; ++e)
            pp[kb + (jb - jb0) * 8 + e] = (ushort)(i | ((j0 + e) << 8));
    }
    const int h = (8 - (i & 7)) & 7;
    const int rb = 7936 + off_r;
    for (int e = 0; e < h; ++e)
        pp[rb + e] = (ushort)(i | ((i + e) << 8));
}

// ---------- phase 1b: W -> bf16, K-tiled in PERMUTED order ----------
__global__ void build_wt(const float* __restrict__ A, const float* __restrict__ B,
                         const ushort* __restrict__ pp, ushort* __restrict__ wt) {
    int e  = blockIdx.x * 256 + threadIdx.x;   // 131*8192 = 4192*256 exactly
    int kt = e >> 13;
    int p  = e & 8191;
    int m  = p >> 6;
    int kl = p & 63;
    uint pr = pp[kt * 64 + kl];
    uint i = pr & 0xFFu, j = pr >> 8;
    float v;
    if (j == 0xFFu) v = A[m * 128 + i];
    else {
        int s = (int)(i * (257 - i) / 2 + (j - i));
        v = B[(size_t)m * S_ + s];
    }
    wt[e] = f2bf(v);
}

// ---------- phase 2: fused MFMA GEMM, 3-phase branch-free K-loop ----------
__global__ __launch_bounds__(256) void gemm_mfma(
    const float*  __restrict__ x,
    const ushort* __restrict__ wt,
    const ushort* __restrict__ pp,
    float* __restrict__ out)
{
    __shared__ ushort xt[64 * LD];     // xt[n*LD + r] = bf16 x[r][b0+n], 17 KB

    const int t    = threadIdx.x;
    const int b0   = blockIdx.x * 64;
    const int sp   = blockIdx.y;
    const int kt0  = sp * 33;
    const int kt1  = (sp == 3) ? NKT : kt0 + 33;
    const int lane = t & 63;
    const int w    = t >> 6;
    const int wm   = w >> 1, wn = w & 1;
    const int l16  = lane & 15, quad = lane >> 4;
    const int n    = t & 63;

    // ---- stage xt: coalesced dword loads, RNE, packed b128 LDS writes ----
    #pragma unroll
    for (int c = 0; c < 4; ++c) {
        const int rb = w * 32 + c * 8;
        uint ow[4];
        #pragma unroll
        for (int p = 0; p < 4; ++p) {
            const ushort u0 = f2bf(x[(size_t)(rb + 2 * p) * BATCH_ + b0 + n]);
            const ushort u1 = f2bf(x[(size_t)(rb + 2 * p + 1) * BATCH_ + b0 + n]);
            ow[p] = (uint)u0 | ((uint)u1 << 16);
        }
        __builtin_memcpy(&xt[n * LD + rb], ow, 16);
    }
    __syncthreads();

    f32x4 acc[4][2];
    #pragma unroll
    for (int mt = 0; mt < 4; ++mt)
        #pragma unroll
        for (int nt = 0; nt < 2; ++nt)
            acc[mt][nt] = (f32x4){0.f, 0.f, 0.f, 0.f};

    const ushort* xr0 = xt + (wn * 32 + l16) * LD;
    const ushort* xr1 = xr0 + 16 * LD;
    const ushort* abase = wt + (size_t)quad * 8 + (size_t)(wm * 64 + l16) * 64;

    // phase boundaries within this split
    const int e_id = (kt1 < 2)   ? kt1 : 2;     // identity: [kt0, e_id)
    const int s_ni = (kt0 > 2)   ? kt0 : 2;     // NICE:     [s_ni, e_ni)
    const int e_ni = (kt1 < 124) ? kt1 : 124;
    const int s_rg = (kt0 > 124) ? kt0 : 124;   // ragged:   [s_rg, kt1)

    // ================= identity steps (kt = 0,1; sp==0 only) =================
    for (int kt = kt0; kt < e_id; ++kt) {
        short8 af[8];
        const ushort* ab = abase + (size_t)kt * 8192;
        #pragma unroll
        for (int kk = 0; kk < 2; ++kk)
            #pragma unroll
            for (int mt = 0; mt < 4; ++mt)
                af[kk * 4 + mt] = *(const short8*)(ab + mt * 1024 + kk * 32);
        short8 bfr[2][2];
        #pragma unroll
        for (int kk = 0; kk < 2; ++kk) {
            const int off = kt * 64 + kk * 32 + quad * 8;
            bfr[kk][0] = *(const short8*)(xr0 + off);
            bfr[kk][1] = *(const short8*)(xr1 + off);
        }
        #pragma unroll
        for (int kk = 0; kk < 2; ++kk)
            #pragma unroll
            for (int mt = 0; mt < 4; ++mt)
                #pragma unroll
                for (int nt = 0; nt < 2; ++nt)
                    acc[mt][nt] = __builtin_amdgcn_mfma_f32_16x16x32_bf16(
                        af[kk * 4 + mt], bfr[kk][nt], acc[mt][nt], 0, 0, 0);
    }

    // ================= NICE steps (branch-free body) =================
    {
        uint prc0 = *(const uint*)(pp + (s_ni * 64 + quad * 8));
        uint prc1 = *(const uint*)(pp + (s_ni * 64 + 32 + quad * 8));
        for (int kt = s_ni; kt < e_ni; ++kt) {
            // prefetch next step's pair words (always in-bounds: kt+1 <= 124)
            const uint prn0 = *(const uint*)(pp + ((kt + 1) * 64 + quad * 8));
            const uint prn1 = *(const uint*)(pp + ((kt + 1) * 64 + 32 + quad * 8));

            // af loads (global, L2-resident)
            short8 af[8];
            const ushort* ab = abase + (size_t)kt * 8192;
            #pragma unroll
            for (int kk = 0; kk < 2; ++kk)
                #pragma unroll
                for (int mt = 0; mt < 4; ++mt)
                    af[kk * 4 + mt] = *(const short8*)(ab + mt * 1024 + kk * 32);

            // gen: all LDS reads independent -> batched lgkm window
            const uint i0a = prc0 & 0xFFu, j0a = (prc0 >> 8) & 0xFFu;
            const uint i0b = prc1 & 0xFFu, j0b = (prc1 >> 8) & 0xFFu;
            const ushort xia0 = xr0[i0a], xia1 = xr1[i0a];
            const ushort xib0 = xr0[i0b], xib1 = xr1[i0b];
            uint wa0[4], wa1[4], wb0[4], wb1[4];
            __builtin_memcpy(wa0, xr0 + j0a, 16);
            __builtin_memcpy(wa1, xr1 + j0a, 16);
            __builtin_memcpy(wb0, xr0 + j0b, 16);
            __builtin_memcpy(wb1, xr1 + j0b, 16);

            short8 bfr[2][2];
            #pragma unroll
            for (int v = 0; v < 4; ++v) {
                const uint* wsx = (v == 0) ? wa0 : (v == 1) ? wa1 : (v == 2) ? wb0 : wb1;
                const ushort xis = (v == 0) ? xia0 : (v == 1) ? xia1 : (v == 2) ? xib0 : xib1;
                const float xi = bf2f(xis);
                const f32x2 xi2 = {xi, xi};
                uint ow[4];
                #pragma unroll
                for (int p = 0; p < 4; ++p) {
                    const uint lo = wsx[p] << 16;
                    const uint hi = wsx[p] & 0xFFFF0000u;
                    f32x2 a;
                    { float fl, fh;
                      __builtin_memcpy(&fl, &lo, 4);
                      __builtin_memcpy(&fh, &hi, 4);
                      a.x = fl; a.y = fh; }
                    const f32x2 o = a * xi2;                      // v_pk_mul_f32
                    ow[p] = __builtin_amdgcn_perm(fbits(o.y), fbits(o.x),
                                                  0x07060302u);   // hi16|hi16
                }
                __builtin_memcpy(&bfr[v >> 1][v & 1], ow, 16);
            }

            #pragma unroll
            for (int kk = 0; kk < 2; ++kk)
                #pragma unroll
                for (int mt = 0; mt < 4; ++mt)
                    #pragma unroll
                    for (int nt = 0; nt < 2; ++nt)
                        acc[mt][nt] = __builtin_amdgcn_mfma_f32_16x16x32_bf16(
                            af[kk * 4 + mt], bfr[kk][nt], acc[mt][nt], 0, 0, 0);

            prc0 = prn0;
            prc1 = prn1;
        }
    }

    // ================= ragged steps (kt = 124..130; sp==3 only) =================
    for (int kt = s_rg; kt < kt1; ++kt) {
        short8 af[8];
        const ushort* ab = abase + (size_t)kt * 8192;
        #pragma unroll
        for (int kk = 0; kk < 2; ++kk)
            #pragma unroll
            for (int mt = 0; mt < 4; ++mt)
                af[kk * 4 + mt] = *(const short8*)(ab + mt * 1024 + kk * 32);

        short8 bfr[2][2];
        #pragma unroll
        for (int kk = 0; kk < 2; ++kk) {
            const int k0 = kt * 64 + kk * 32 + quad * 8;
            const uint4 pk = *(const uint4*)(pp + k0);
            const uint pr4[4] = {pk.x, pk.y, pk.z, pk.w};
            #pragma unroll
            for (int nt = 0; nt < 2; ++nt) {
                const ushort* xr = nt ? xr1 : xr0;
                float prods[8];
                #pragma unroll
                for (int e = 0; e < 8; ++e) {
                    const uint ent = (pr4[e >> 1] >> ((e & 1) * 16)) & 0xFFFFu;
                    prods[e] = bf2f(xr[ent & 0xFFu]) * bf2f(xr[ent >> 8]);
                }
                uint ow[4];
                #pragma unroll
                for (int p = 0; p < 4; ++p)
                    ow[p] = __builtin_amdgcn_perm(fbits(prods[2 * p + 1]),
                                                  fbits(prods[2 * p]),
                                                  0x07060302u);
                __builtin_memcpy(&bfr[kk][nt], ow, 16);
            }
        }

        #pragma unroll
        for (int kk = 0; kk < 2; ++kk)
            #pragma unroll
            for (int mt = 0; mt < 4; ++mt)
                #pragma unroll
                for (int nt = 0; nt < 2; ++nt)
                    acc[mt][nt] = __builtin_amdgcn_mfma_f32_16x16x32_bf16(
                        af[kk * 4 + mt], bfr[kk][nt], acc[mt][nt], 0, 0, 0);
    }

    // ---- epilogue: atomic accumulate (C/D: col=lane&15, row=quad*4+reg) ----
    #pragma unroll
    for (int mt = 0; mt < 4; ++mt) {
        #pragma unroll
        for (int nt = 0; nt < 2; ++nt) {
            const int mbase = wm * 64 + mt * 16 + quad * 4;
            const size_t col = (size_t)b0 + wn * 32 + nt * 16 + l16;
            #pragma unroll
            for (int r = 0; r < 4; ++r)
                unsafeAtomicAdd(&out[(size_t)(mbase + r) * BATCH_ + col],
                                acc[mt][nt][r]);
        }
    }
}

extern "C" void kernel_launch(void* const* d_in, const int* in_sizes, int n_in,
                              void* d_out, int out_size, void* d_ws, size_t ws_size,
                              hipStream_t stream) {
    const float* x = (const float*)d_in[0];   // [128, 16384]
    const float* A = (const float*)d_in[1];   // [128, 128]
    const float* B = (const float*)d_in[2];   // [128, 8256]
    float* out = (float*)d_out;               // [128, 16384]

    ushort* wt = (ushort*)d_ws;
    ushort* pp = (ushort*)((char*)d_ws + PP_OFF);

    hipMemsetAsync(out, 0, (size_t)N_ * BATCH_ * sizeof(float), stream);
    build_perm<<<1, 128, 0, stream>>>(pp);
    build_wt<<<4192, 256, 0, stream>>>(A, B, pp, wt);
    gemm_mfma<<<dim3(BATCH_ / 64, NSPLIT), 256, 0, stream>>>(x, wt, pp, out);
}

// Round 9
// 126.649 us; speedup vs baseline: 3.2260x; 1.6220x over previous
//
#include <hip/hip_runtime.h>

// out[128,16384] = [A|B](128x8384) @ [x; x2](8384x16384), bf16 MFMA.
// Round 9 = round 8 + latency-chain removal:
//   - wt in COALESCED layout [kt][kk][wm][mt][lane]: af loads are lane-linear
//     (base + imm offsets, 8 cache lines/instr instead of 16)
//   - af register double-buffer (afA/afB), NICE loop manually 2-unrolled:
//     step kt consumes regs prefetched at kt-1 -> L2 latency hidden
//   - pp compacted to 2KB LDS table ppc[kt*4+quad] (i0a|j0a|i0b|j0b bytes),
//     prefetched one step ahead -> gen chain starts at LDS not global
//   - 128x128 block tile (512 thr, 8 waves), split-K x2 (grid 256 = 2 blocks/CU):
//     halves wt L2 traffic (540->270 MB) and prologue/atomic overhead
// DO NOT add __launch_bounds__ min-waves: (256,8) clamped VGPR -> spills (r6).
// K permutation: identity k'<128 (steps 0-1) | NICE [128,7936) (steps 2-123,
// uniform i, aligned j-octet) | RAGGED [7936,8384) (steps 124-130, gather).

constexpr int N_     = 128;
constexpr int S_     = 8256;
constexpr int BATCH_ = 16384;
constexpr int KTOT   = 8384;         // 131*64
constexpr int NKT    = 131;
constexpr int LD     = 136;          // xt row stride (ushorts); rows 272B = 17x16B
constexpr size_t WT_BYTES = (size_t)KTOT * 128 * 2;
constexpr size_t PP_OFF   = WT_BYTES;

typedef __attribute__((ext_vector_type(8))) short short8;
typedef __attribute__((ext_vector_type(4))) float f32x4;
typedef __attribute__((ext_vector_type(2))) float f32x2;

__device__ __forceinline__ float bf2f(ushort h) {
    unsigned u = (unsigned)h << 16;
    float f;
    __builtin_memcpy(&f, &u, 4);
    return f;
}
__device__ __forceinline__ ushort f2bf(float f) {   // RNE (staging/build only)
    unsigned u;
    __builtin_memcpy(&u, &f, 4);
    u = (u + 0x7FFFu + ((u >> 16) & 1u)) >> 16;
    return (ushort)u;
}
__device__ __forceinline__ uint fbits(float f) {
    uint u; __builtin_memcpy(&u, &f, 4); return u;
}

// ---------- phase 1a: permuted pair table pp[k'] = i | (j<<8) ----------
__global__ void build_perm(ushort* __restrict__ pp) {
    int i = threadIdx.x;
    if (i >= 128) return;
    pp[i] = (ushort)(i | (0xFFu << 8));
    int off_n = 0, off_r = 0;
    for (int q = 0; q < i; ++q) {
        off_n += 16 - ((q + 7) >> 3);
        off_r += (8 - (q & 7)) & 7;
    }
    const int jb0 = (i + 7) >> 3;
    const int kb = 128 + off_n * 8;
    for (int jb = jb0; jb < 16; ++jb) {
        const int j0 = jb * 8;
        for (int e = 0; e < 8; ++e)
            pp[kb + (jb - jb0) * 8 + e] = (ushort)(i | ((j0 + e) << 8));
    }
    const int h = (8 - (i & 7)) & 7;
    const int rb = 7936 + off_r;
    for (int e = 0; e < h; ++e)
        pp[rb + e] = (ushort)(i | ((i + e) << 8));
}

// ---------- phase 1b: W -> bf16, COALESCED per-fragment layout ----------
// elem e = kt*8192 + (((kk*2+wm)*4+mt)*64 + lane)*8 + el  holds
// W[m = wm*64+mt*16+(lane&15)][ perm(kt*64 + kk*32 + (lane>>4)*8 + el) ]
__global__ void build_wt(const float* __restrict__ A, const float* __restrict__ B,
                         const ushort* __restrict__ pp, ushort* __restrict__ wt) {
    int e  = blockIdx.x * 256 + threadIdx.x;   // 131*8192 = 4192*256 exactly
    int kt = e >> 13;
    int r  = e & 8191;
    int kk = r >> 12;
    int wmm = (r >> 11) & 1;
    int mt = (r >> 9) & 3;
    int lane = (r >> 3) & 63;
    int el = r & 7;
    int m  = wmm * 64 + mt * 16 + (lane & 15);
    int k  = kt * 64 + kk * 32 + (lane >> 4) * 8 + el;
    uint pr = pp[k];
    uint i = pr & 0xFFu, j = pr >> 8;
    float v;
    if (j == 0xFFu) v = A[m * 128 + i];
    else {
        int s = (int)(i * (257 - i) / 2 + (j - i));
        v = B[(size_t)m * S_ + s];
    }
    wt[e] = f2bf(v);
}

// A-frags for step kt: 8 lane-linear b128 loads (coalesced layout).
__device__ __forceinline__ void load_af(short8 af[8], const ushort* __restrict__ wt,
                                        int kt, int wm, int lane) {
    const ushort* ab = wt + ((size_t)kt << 13) + (wm << 11) + (lane << 3);
    #pragma unroll
    for (int kk = 0; kk < 2; ++kk)
        #pragma unroll
        for (int mt = 0; mt < 4; ++mt)
            af[kk * 4 + mt] = *(const short8*)(ab + (kk << 12) + (mt << 9));
}

// NICE-step: gen B-frags from compact pair word + MFMA.
__device__ __forceinline__ void step_nice(f32x4 acc[4][2], const short8 af[8],
                                          uint prc, const ushort* __restrict__ xr0,
                                          const ushort* __restrict__ xr1) {
    const uint i0a = prc & 0xFFu, j0a = (prc >> 8) & 0xFFu;
    const uint i0b = (prc >> 16) & 0xFFu, j0b = prc >> 24;
    // all 8 LDS reads independent -> one lgkm window
    const ushort xia0 = xr0[i0a], xia1 = xr1[i0a];
    const ushort xib0 = xr0[i0b], xib1 = xr1[i0b];
    uint wa0[4], wa1[4], wb0[4], wb1[4];
    __builtin_memcpy(wa0, xr0 + j0a, 16);
    __builtin_memcpy(wa1, xr1 + j0a, 16);
    __builtin_memcpy(wb0, xr0 + j0b, 16);
    __builtin_memcpy(wb1, xr1 + j0b, 16);

    short8 bfr[2][2];
    #pragma unroll
    for (int v = 0; v < 4; ++v) {
        const uint*  wsx = (v == 0) ? wa0 : (v == 1) ? wa1 : (v == 2) ? wb0 : wb1;
        const ushort xis = (v == 0) ? xia0 : (v == 1) ? xia1 : (v == 2) ? xib0 : xib1;
        const float xi = bf2f(xis);
        const f32x2 xi2 = {xi, xi};
        uint ow[4];
        #pragma unroll
        for (int p = 0; p < 4; ++p) {
            const uint lo = wsx[p] << 16;
            const uint hi = wsx[p] & 0xFFFF0000u;
            f32x2 a;
            { float fl, fh;
              __builtin_memcpy(&fl, &lo, 4);
              __builtin_memcpy(&fh, &hi, 4);
              a.x = fl; a.y = fh; }
            const f32x2 o = a * xi2;                      // v_pk_mul_f32
            ow[p] = __builtin_amdgcn_perm(fbits(o.y), fbits(o.x),
                                          0x07060302u);   // hi16|hi16 trunc pack
        }
        __builtin_memcpy(&bfr[v >> 1][v & 1], ow, 16);
    }
    #pragma unroll
    for (int kk = 0; kk < 2; ++kk)
        #pragma unroll
        for (int mt = 0; mt < 4; ++mt)
            #pragma unroll
            for (int nt = 0; nt < 2; ++nt)
                acc[mt][nt] = __builtin_amdgcn_mfma_f32_16x16x32_bf16(
                    af[kk * 4 + mt], bfr[kk][nt], acc[mt][nt], 0, 0, 0);
}

// ---------- phase 2: fused MFMA GEMM, 128x128 tile, pipelined K-loop ----------
__global__ __launch_bounds__(512) void gemm_mfma(
    const float*  __restrict__ x,
    const ushort* __restrict__ wt,
    const ushort* __restrict__ pp,
    float* __restrict__ out)
{
    __shared__ ushort xt[128 * LD];    // 34.8 KB: xt[n*LD + r] = bf16 x[r][b0+n]
    __shared__ uint   ppc[NKT * 4];    // 2.1 KB: i0a|j0a<<8|i0b<<16|j0b<<24 per (kt,quad)

    const int t    = threadIdx.x;
    const int b0   = blockIdx.x * 128;
    const int sp   = blockIdx.y;
    const int kt0  = sp ? 66 : 0;
    const int kt1  = sp ? NKT : 66;
    const int lane = t & 63;
    const int w    = t >> 6;
    const int wm   = w >> 2, wn = w & 3;
    const int l16  = lane & 15, quad = lane >> 4;

    // ---- stage xt: coalesced global reads, RNE, b128 LDS writes ----
    {
        const int n = t & 127, g = t >> 7;
        #pragma unroll
        for (int c = 0; c < 4; ++c) {
            const int rb = g * 32 + c * 8;
            uint ow[4];
            #pragma unroll
            for (int p = 0; p < 4; ++p) {
                const ushort u0 = f2bf(x[(size_t)(rb + 2 * p) * BATCH_ + b0 + n]);
                const ushort u1 = f2bf(x[(size_t)(rb + 2 * p + 1) * BATCH_ + b0 + n]);
                ow[p] = (uint)u0 | ((uint)u1 << 16);
            }
            __builtin_memcpy(&xt[n * LD + rb], ow, 16);
        }
    }
    // ---- stage ppc ----
    for (int idx = t; idx < NKT * 4; idx += 512) {
        const int kt = idx >> 2, q = idx & 3;
        const uint w0 = *(const uint*)(pp + kt * 64 + q * 8);
        const uint w1 = *(const uint*)(pp + kt * 64 + 32 + q * 8);
        ppc[idx] = (w0 & 0xFFFFu) | ((w1 & 0xFFFFu) << 16);
    }
    __syncthreads();

    f32x4 acc[4][2];
    #pragma unroll
    for (int mt = 0; mt < 4; ++mt)
        #pragma unroll
        for (int nt = 0; nt < 2; ++nt)
            acc[mt][nt] = (f32x4){0.f, 0.f, 0.f, 0.f};

    const ushort* xr0 = xt + (wn * 32 + l16) * LD;
    const ushort* xr1 = xr0 + 16 * LD;

    // ================= identity steps (kt = 0,1; sp==0 only) =================
    if (sp == 0) {
        for (int kt = 0; kt < 2; ++kt) {
            short8 af[8];
            load_af(af, wt, kt, wm, lane);
            short8 bfr[2][2];
            #pragma unroll
            for (int kk = 0; kk < 2; ++kk) {
                const int off = kt * 64 + kk * 32 + quad * 8;
                bfr[kk][0] = *(const short8*)(xr0 + off);
                bfr[kk][1] = *(const short8*)(xr1 + off);
            }
            #pragma unroll
            for (int kk = 0; kk < 2; ++kk)
                #pragma unroll
                for (int mt = 0; mt < 4; ++mt)
                    #pragma unroll
                    for (int nt = 0; nt < 2; ++nt)
                        acc[mt][nt] = __builtin_amdgcn_mfma_f32_16x16x32_bf16(
                            af[kk * 4 + mt], bfr[kk][nt], acc[mt][nt], 0, 0, 0);
        }
    }

    // ================= NICE steps, software-pipelined =================
    {
        const int s_ni = (kt0 > 2) ? kt0 : 2;
        const int e_ni = (kt1 < 124) ? kt1 : 124;
        int kt = s_ni;
        if (kt < e_ni) {
            short8 afA[8], afB[8];
            load_af(afA, wt, kt, wm, lane);
            uint prc = ppc[kt * 4 + quad];
            while (true) {
                {   // consume afA, prefetch afB
                    const int ktn = (kt + 1 < e_ni) ? kt + 1 : kt;
                    load_af(afB, wt, ktn, wm, lane);
                    const uint prn = ppc[ktn * 4 + quad];
                    step_nice(acc, afA, prc, xr0, xr1);
                    prc = prn; ++kt;
                }
                if (kt >= e_ni) break;
                {   // consume afB, prefetch afA
                    const int ktn = (kt + 1 < e_ni) ? kt + 1 : kt;
                    load_af(afA, wt, ktn, wm, lane);
                    const uint prn = ppc[ktn * 4 + quad];
                    step_nice(acc, afB, prc, xr0, xr1);
                    prc = prn; ++kt;
                }
                if (kt >= e_ni) break;
            }
        }
    }

    // ================= ragged steps (kt = 124..130; sp==1 only) =================
    if (sp == 1) {
        for (int kt = 124; kt < NKT; ++kt) {
            short8 af[8];
            load_af(af, wt, kt, wm, lane);
            short8 bfr[2][2];
            #pragma unroll
            for (int kk = 0; kk < 2; ++kk) {
                const int k0 = kt * 64 + kk * 32 + quad * 8;
                const uint4 pk = *(const uint4*)(pp + k0);
                const uint pr4[4] = {pk.x, pk.y, pk.z, pk.w};
                #pragma unroll
                for (int nt = 0; nt < 2; ++nt) {
                    const ushort* xr = nt ? xr1 : xr0;
                    float prods[8];
                    #pragma unroll
                    for (int e = 0; e < 8; ++e) {
                        const uint ent = (pr4[e >> 1] >> ((e & 1) * 16)) & 0xFFFFu;
                        prods[e] = bf2f(xr[ent & 0xFFu]) * bf2f(xr[ent >> 8]);
                    }
                    uint ow[4];
                    #pragma unroll
                    for (int p = 0; p < 4; ++p)
                        ow[p] = __builtin_amdgcn_perm(fbits(prods[2 * p + 1]),
                                                      fbits(prods[2 * p]),
                                                      0x07060302u);
                    __builtin_memcpy(&bfr[kk][nt], ow, 16);
                }
            }
            #pragma unroll
            for (int kk = 0; kk < 2; ++kk)
                #pragma unroll
                for (int mt = 0; mt < 4; ++mt)
                    #pragma unroll
                    for (int nt = 0; nt < 2; ++nt)
                        acc[mt][nt] = __builtin_amdgcn_mfma_f32_16x16x32_bf16(
                            af[kk * 4 + mt], bfr[kk][nt], acc[mt][nt], 0, 0, 0);
        }
    }

    // ---- epilogue: atomic accumulate (C/D: col=lane&15, row=quad*4+reg) ----
    #pragma unroll
    for (int mt = 0; mt < 4; ++mt) {
        #pragma unroll
        for (int nt = 0; nt < 2; ++nt) {
            const int mbase = wm * 64 + mt * 16 + quad * 4;
            const size_t col = (size_t)b0 + wn * 32 + nt * 16 + l16;
            #pragma unroll
            for (int r = 0; r < 4; ++r)
                unsafeAtomicAdd(&out[(size_t)(mbase + r) * BATCH_ + col],
                                acc[mt][nt][r]);
        }
    }
}

extern "C" void kernel_launch(void* const* d_in, const int* in_sizes, int n_in,
                              void* d_out, int out_size, void* d_ws, size_t ws_size,
                              hipStream_t stream) {
    const float* x = (const float*)d_in[0];   // [128, 16384]
    const float* A = (const float*)d_in[1];   // [128, 128]
    const float* B = (const float*)d_in[2];   // [128, 8256]
    float* out = (float*)d_out;               // [128, 16384]

    ushort* wt = (ushort*)d_ws;
    ushort* pp = (ushort*)((char*)d_ws + PP_OFF);

    hipMemsetAsync(out, 0, (size_t)N_ * BATCH_ * sizeof(float), stream);
    build_perm<<<1, 128, 0, stream>>>(pp);
    build_wt<<<4192, 256, 0, stream>>>(A, B, pp, wt);
    gemm_mfma<<<dim3(BATCH_ / 128, 2), 512, 0, stream>>>(x, wt, pp, out);
}